// Round 4
// baseline (47.160 us; speedup 1.0000x reference)
//
#include <hip/hip_runtime.h>
#include <hip/hip_bf16.h>
#include <math.h>

// InfiniteContextAttention — causal mask reaches only keys 0..15 (= compressed_k/v[:,:, :16]).
// Pipeline: q = hidden @ Wq^T -> 16-key causal attention -> out = attn @ Wo^T.
//
// GEMM v4 (MFMA bf16, occupancy x2): C[32][4096] = A[32][4096] @ W[4096][4096]^T.
// 1024 blocks = 64 col-groups x 16 K-slices; block = 4 waves = 64 cols, K-slice 256.
// 16 KB LDS + launch_bounds(256,4) -> 4 blocks/CU, 4 waves/SIMD.
// A-slice staged once -> bf16 XOR-swizzled LDS (one barrier). W streamed
// global->reg (distance-2 prefetch) ->bf16->MFMA, no LDS, no K-loop barriers.
// Partials [16][32][4096]; q-reduce fused into attn; reduce kernel for out.

#define HID 4096
#define NROW 32
#define NSLICE 16
#define KSL 256
#define NSTEP (KSL / 32)          // 8 MFMA K-steps
#define PART_STRIDE (NROW * HID)  // 131072 floats per slice

typedef __attribute__((ext_vector_type(8))) short short8;
typedef __attribute__((ext_vector_type(4))) float f32x4;

__device__ __forceinline__ unsigned short f2bf(float x) {
    __hip_bfloat16 h = __float2bfloat16(x);
    return __builtin_bit_cast(unsigned short, h);
}

__global__ __launch_bounds__(256, 4)
void gemm_mfma(const float* __restrict__ A,   // [32][4096] fp32
               const float* __restrict__ W,   // [4096][4096] fp32
               float* __restrict__ P)         // [16][32][4096] fp32 partials
{
    __shared__ short As[NROW * KSL];  // 16 KB bf16, XOR-swizzled (T2)
    const int tid  = threadIdx.x;
    const int lane = tid & 63;
    const int wv   = tid >> 6;            // wave 0..3 -> 16-col tile
    const int cg   = blockIdx.x & 63;     // column group (64 cols)
    const int sl   = blockIdx.x >> 6;     // K-slice 0..15
    const int ks   = sl * KSL;

    // ---- stage A slice (fp32 -> bf16, swizzled): row = tid>>3, 8 threads/row ----
    {
        const int r  = tid >> 3;          // row 0..31
        const int c8 = tid & 7;           // float4 subgroup within row
        const float* src = A + (size_t)r * HID + ks + c8 * 4;
        char* lb = (char*)As + r * (KSL * 2);   // 512 B per row
        const int rx = (r & 7) << 4;
#pragma unroll
        for (int i = 0; i < 8; ++i) {
            float4 v = *(const float4*)(src + i * 32);
            unsigned long long pk =
                  (unsigned long long)f2bf(v.x)
                | ((unsigned long long)f2bf(v.y) << 16)
                | ((unsigned long long)f2bf(v.z) << 32)
                | ((unsigned long long)f2bf(v.w) << 48);
            int byte = ((c8 + 8 * i) * 8) ^ rx;  // 8B granule, bits 4-6 swizzled
            *(unsigned long long*)(lb + byte) = pk;
        }
    }
    __syncthreads();  // the only barrier

    const int l15 = lane & 15, lq = lane >> 4, l7 = lane & 7;
    const int jcol = cg * 64 + wv * 16 + l15;
    const float* wp = W + (size_t)jcol * HID + ks + lq * 8;
    const char* lA0 = (const char*)As + l15 * (KSL * 2);
    const char* lA1 = (const char*)As + (16 + l15) * (KSL * 2);
    const int rswz = l7 << 4;   // (row&7)<<4, same for row l15 and 16+l15

    f32x4 acc0 = {0.f, 0.f, 0.f, 0.f}, acc1 = {0.f, 0.f, 0.f, 0.f};

    // distance-2 W prefetch pipeline (2 float4/step in flight per depth)
    float4 w0a = *(const float4*)(wp);
    float4 w0b = *(const float4*)(wp + 4);
    float4 w1a = *(const float4*)(wp + 32);
    float4 w1b = *(const float4*)(wp + 36);

#pragma unroll
    for (int kk = 0; kk < NSTEP; ++kk) {
        float4 nA, nB;
        if (kk < NSTEP - 2) {
            nA = *(const float4*)(wp + (kk + 2) * 32);
            nB = *(const float4*)(wp + (kk + 2) * 32 + 4);
        }
        const int byte = ((kk * 64) + (lq * 16)) ^ rswz;
        short8 a0 = *(const short8*)(lA0 + byte);
        short8 a1 = *(const short8*)(lA1 + byte);
        short8 b;
        b[0] = (short)f2bf(w0a.x); b[1] = (short)f2bf(w0a.y);
        b[2] = (short)f2bf(w0a.z); b[3] = (short)f2bf(w0a.w);
        b[4] = (short)f2bf(w0b.x); b[5] = (short)f2bf(w0b.y);
        b[6] = (short)f2bf(w0b.z); b[7] = (short)f2bf(w0b.w);
        acc0 = __builtin_amdgcn_mfma_f32_16x16x32_bf16(a0, b, acc0, 0, 0, 0);
        acc1 = __builtin_amdgcn_mfma_f32_16x16x32_bf16(a1, b, acc1, 0, 0, 0);
        w0a = w1a; w0b = w1b; w1a = nA; w1b = nB;
    }

    // ---- epilogue: C/D layout col=lane&15, row=(lane>>4)*4+reg (m89-verified) ----
    float* pout = P + (size_t)sl * PART_STRIDE + jcol;
#pragma unroll
    for (int rr = 0; rr < 4; ++rr) {
        pout[(size_t)(lq * 4 + rr) * HID]      = acc0[rr];
        pout[(size_t)(16 + lq * 4 + rr) * HID] = acc1[rr];
    }
}

// One wave per (b,h,i): fuses the 16-slice q-reduction with 16-key causal attention.
__global__ __launch_bounds__(256)
void attn16_kernel(const float* __restrict__ P,   // q partials [16][32][4096]
                   const float* __restrict__ ck,
                   const float* __restrict__ cv,
                   float* __restrict__ o)          // [32][4096]
{
    const int lane = threadIdx.x & 63;
    const int g = blockIdx.x * 4 + (threadIdx.x >> 6);  // 0..1023
    const int b = g >> 9;
    const int h = (g >> 4) & 31;
    const int i = g & 15;

    const size_t qoff = ((size_t)(b * 16 + i)) * HID + h * 128 + 2 * lane;
    float2 q2 = {0.f, 0.f};
#pragma unroll
    for (int s = 0; s < NSLICE; ++s) {
        float2 p = *(const float2*)(P + (size_t)s * PART_STRIDE + qoff);
        q2.x += p.x; q2.y += p.y;
    }
    const size_t kvoff = ((size_t)(b * 32 + h)) * 2048 * 128 + 2 * lane;
    const float* kp = ck + kvoff;
    const float* vp = cv + kvoff;

    float e[16];
#pragma unroll
    for (int s = 0; s < 16; ++s) {
        float2 k2 = *(const float2*)(kp + (size_t)s * 128);
        float p = q2.x * k2.x + q2.y * k2.y;
#pragma unroll
        for (int m = 32; m >= 1; m >>= 1) p += __shfl_xor(p, m, 64);
        e[s] = (s <= i) ? p * 0.08838834764831845f : -3.4e38f;  // i wave-uniform
    }
    float mx = e[0];
#pragma unroll
    for (int s = 1; s < 16; ++s) mx = fmaxf(mx, e[s]);
    float den = 0.f;
#pragma unroll
    for (int s = 0; s < 16; ++s) { e[s] = __expf(e[s] - mx); den += e[s]; }
    const float inv = 1.0f / den;

    float ox = 0.f, oy = 0.f;
#pragma unroll
    for (int s = 0; s < 16; ++s) {
        float2 v2 = *(const float2*)(vp + (size_t)s * 128);
        ox += e[s] * v2.x;
        oy += e[s] * v2.y;
    }
    float2 res; res.x = ox * inv; res.y = oy * inv;
    *(float2*)(o + qoff) = res;
}

// out[i] = sum over 16 slices of P[s][i]; 32768 float4s.
__global__ __launch_bounds__(256)
void reduce_kernel(const float* __restrict__ P, float* __restrict__ out)
{
    const int idx = blockIdx.x * 256 + threadIdx.x;  // float4 index
    const float4* p4 = (const float4*)P;
    float4 s = p4[idx];
#pragma unroll
    for (int t = 1; t < NSLICE; ++t) {
        float4 v = p4[idx + t * (PART_STRIDE / 4)];
        s.x += v.x; s.y += v.y; s.z += v.z; s.w += v.w;
    }
    ((float4*)out)[idx] = s;
}

extern "C" void kernel_launch(void* const* d_in, const int* in_sizes, int n_in,
                              void* d_out, int out_size, void* d_ws, size_t ws_size,
                              hipStream_t stream) {
    const float* hidden = (const float*)d_in[0];  // [2][16][4096]
    const float* ck     = (const float*)d_in[3];  // [2][32][2048][128]
    const float* cv     = (const float*)d_in[4];
    const float* Wq     = (const float*)d_in[5];  // [4096][4096]
    const float* Wo     = (const float*)d_in[8];
    float* out  = (float*)d_out;                  // [2][16][4096]
    float* part = (float*)d_ws;                   // [16][32][4096] = 8 MB
    float* abuf = part + NSLICE * PART_STRIDE;    // [32][4096] attn output

    hipLaunchKernelGGL(gemm_mfma,     dim3(1024), dim3(256), 0, stream, hidden, Wq, part);
    hipLaunchKernelGGL(attn16_kernel, dim3(256),  dim3(256), 0, stream, part, ck, cv, abuf);
    hipLaunchKernelGGL(gemm_mfma,     dim3(1024), dim3(256), 0, stream, abuf, Wo, part);
    hipLaunchKernelGGL(reduce_kernel, dim3(128),  dim3(256), 0, stream, part, out);
}

// Round 5
// 46.051 us; speedup vs baseline: 1.0241x; 1.0241x over previous
//
#include <hip/hip_runtime.h>
#include <hip/hip_bf16.h>
#include <math.h>

// InfiniteContextAttention — causal mask reaches only keys 0..15 (= compressed_k/v[:,:, :16]).
// Pipeline: cvt(hidden->bf16) -> q = hbf @ Wq^T -> 16-key attention (bf16 out) -> out = abf @ Wo^T.
//
// GEMM v5: in-block K-split, no partials. 256 blocks x 512 thr (8 waves).
// Block owns 16 cols; wave wv owns K-slice [wv*512, wv*512+512) -> 16 MFMA steps.
// A read as bf16 straight from global (256 KB, L2-resident) -> no staging LDS,
// no barriers in K-loop. W streamed global->reg (depth-2) -> cvt_pk bf16 -> MFMA.
// Epilogue: per-wave 32x16 tiles to padded LDS, one barrier, 8-way sum, store C.

#define HID 4096
#define NW 8
#define KW 512       // K per wave
#define NSTEP 16     // KW / 32
#define SLAB 580     // reduce slab stride in floats (16 cols * 36 + 4): bank-spread

typedef __attribute__((ext_vector_type(8))) short short8;
typedef __attribute__((ext_vector_type(4))) float f32x4;

__device__ __forceinline__ short8 cvt8(float4 a, float4 b) {
    union { short8 s; __hip_bfloat162 h[4]; } u;
    u.h[0] = __float22bfloat162_rn(make_float2(a.x, a.y));
    u.h[1] = __float22bfloat162_rn(make_float2(a.z, a.w));
    u.h[2] = __float22bfloat162_rn(make_float2(b.x, b.y));
    u.h[3] = __float22bfloat162_rn(make_float2(b.z, b.w));
    return u.s;
}

// hidden [32][4096] fp32 -> bf16. 64 blocks x 256 thr x 8 elems.
__global__ __launch_bounds__(256)
void cvt_kernel(const float* __restrict__ in, __hip_bfloat16* __restrict__ out)
{
    const int idx = blockIdx.x * 256 + threadIdx.x;   // per short8
    float4 v0 = ((const float4*)in)[idx * 2];
    float4 v1 = ((const float4*)in)[idx * 2 + 1];
    ((short8*)out)[idx] = cvt8(v0, v1);
}

__global__ __launch_bounds__(512, 2)
void gemm_mfma(const __hip_bfloat16* __restrict__ Abf,  // [32][4096] bf16
               const float* __restrict__ W,             // [4096][4096] fp32
               float* __restrict__ C)                   // [32][4096] fp32
{
    __shared__ float red[NW * SLAB];  // 18.6 KB
    const int tid  = threadIdx.x;
    const int lane = tid & 63;
    const int wv   = tid >> 6;          // wave 0..7 -> K-slice
    const int l15  = lane & 15;
    const int lq   = lane >> 4;
    const int j0   = blockIdx.x * 16;
    const int jcol = j0 + l15;
    const int kb   = wv * KW;

    const short* a0p = (const short*)Abf + (size_t)l15 * HID + kb + lq * 8;
    const short* a1p = a0p + 16 * HID;
    const float* wp  = W + (size_t)jcol * HID + kb + lq * 8;

    f32x4 acc0 = {0.f, 0.f, 0.f, 0.f}, acc1 = {0.f, 0.f, 0.f, 0.f};

    // depth-2 software pipeline on A (L2) and W (HBM)
    short8 a0c = *(const short8*)(a0p);
    short8 a1c = *(const short8*)(a1p);
    float4 w0c = *(const float4*)(wp);
    float4 w1c = *(const float4*)(wp + 4);
    short8 a0n = *(const short8*)(a0p + 32);
    short8 a1n = *(const short8*)(a1p + 32);
    float4 w0n = *(const float4*)(wp + 32);
    float4 w1n = *(const float4*)(wp + 36);

#pragma unroll
    for (int kk = 0; kk < NSTEP; ++kk) {
        short8 pa0 = {}, pa1 = {};
        float4 pw0 = {}, pw1 = {};
        if (kk < NSTEP - 2) {
            pa0 = *(const short8*)(a0p + (kk + 2) * 32);
            pa1 = *(const short8*)(a1p + (kk + 2) * 32);
            pw0 = *(const float4*)(wp + (kk + 2) * 32);
            pw1 = *(const float4*)(wp + (kk + 2) * 32 + 4);
        }
        short8 b = cvt8(w0c, w1c);
        acc0 = __builtin_amdgcn_mfma_f32_16x16x32_bf16(a0c, b, acc0, 0, 0, 0);
        acc1 = __builtin_amdgcn_mfma_f32_16x16x32_bf16(a1c, b, acc1, 0, 0, 0);
        a0c = a0n; a1c = a1n; w0c = w0n; w1c = w1n;
        a0n = pa0; a1n = pa1; w0n = pw0; w1n = pw1;
    }

    // per-wave tile -> LDS as red[wv][col=l15][row], row-stride 36 (bank-spread)
    // acc layout (m89): col = lane&15, row = (lane>>4)*4 + reg
    float* rb = red + wv * SLAB + l15 * 36;
    *(f32x4*)(rb + lq * 4)      = acc0;   // rows lq*4 + 0..3
    *(f32x4*)(rb + 16 + lq * 4) = acc1;   // rows 16 + lq*4 + 0..3
    __syncthreads();

    const int r = tid >> 4, j = tid & 15;  // 512 threads = 32 rows x 16 cols
    float s = 0.f;
#pragma unroll
    for (int w = 0; w < NW; ++w)
        s += red[w * SLAB + j * 36 + r];
    C[(size_t)r * HID + j0 + j] = s;
}

// One wave per (b,h,i): 16-key causal attention; q fp32 in, bf16 out (feeds gemm2).
__global__ __launch_bounds__(256)
void attn16_kernel(const float* __restrict__ q,
                   const float* __restrict__ ck,
                   const float* __restrict__ cv,
                   __hip_bfloat16* __restrict__ o)   // [32][4096] bf16
{
    const int lane = threadIdx.x & 63;
    const int g = blockIdx.x * 4 + (threadIdx.x >> 6);  // 0..1023
    const int b = g >> 9;
    const int h = (g >> 4) & 31;
    const int i = g & 15;

    const size_t qoff = ((size_t)(b * 16 + i)) * HID + h * 128 + 2 * lane;
    const float2 q2 = *(const float2*)(q + qoff);
    const size_t kvoff = ((size_t)(b * 32 + h)) * 2048 * 128 + 2 * lane;
    const float* kp = ck + kvoff;
    const float* vp = cv + kvoff;

    float e[16];
#pragma unroll
    for (int s = 0; s < 16; ++s) {
        float2 k2 = *(const float2*)(kp + (size_t)s * 128);
        float p = q2.x * k2.x + q2.y * k2.y;
#pragma unroll
        for (int m = 32; m >= 1; m >>= 1) p += __shfl_xor(p, m, 64);
        e[s] = (s <= i) ? p * 0.08838834764831845f : -3.4e38f;  // i wave-uniform
    }
    float mx = e[0];
#pragma unroll
    for (int s = 1; s < 16; ++s) mx = fmaxf(mx, e[s]);
    float den = 0.f;
#pragma unroll
    for (int s = 0; s < 16; ++s) { e[s] = __expf(e[s] - mx); den += e[s]; }
    const float inv = 1.0f / den;

    float ox = 0.f, oy = 0.f;
#pragma unroll
    for (int s = 0; s < 16; ++s) {
        float2 v2 = *(const float2*)(vp + (size_t)s * 128);
        ox += e[s] * v2.x;
        oy += e[s] * v2.y;
    }
    __hip_bfloat162 r2 = __float22bfloat162_rn(make_float2(ox * inv, oy * inv));
    *(__hip_bfloat162*)(o + qoff) = r2;
}

extern "C" void kernel_launch(void* const* d_in, const int* in_sizes, int n_in,
                              void* d_out, int out_size, void* d_ws, size_t ws_size,
                              hipStream_t stream) {
    const float* hidden = (const float*)d_in[0];  // [2][16][4096]
    const float* ck     = (const float*)d_in[3];  // [2][32][2048][128]
    const float* cv     = (const float*)d_in[4];
    const float* Wq     = (const float*)d_in[5];  // [4096][4096]
    const float* Wo     = (const float*)d_in[8];
    float* out = (float*)d_out;                   // [2][16][4096]

    char* ws = (char*)d_ws;
    __hip_bfloat16* hbf = (__hip_bfloat16*)ws;              // 256 KB
    float*          qf  = (float*)(ws + 262144);            // 512 KB
    __hip_bfloat16* abf = (__hip_bfloat16*)(ws + 786432);   // 256 KB

    hipLaunchKernelGGL(cvt_kernel,    dim3(64),  dim3(256), 0, stream, hidden, hbf);
    hipLaunchKernelGGL(gemm_mfma,     dim3(256), dim3(512), 0, stream, hbf, Wq, qf);
    hipLaunchKernelGGL(attn16_kernel, dim3(256), dim3(256), 0, stream, qf, ck, cv, abf);
    hipLaunchKernelGGL(gemm_mfma,     dim3(256), dim3(512), 0, stream, abf, Wo, out);
}